// Round 1
// baseline (216.143 us; speedup 1.0000x reference)
//
#include <hip/hip_runtime.h>
#include <math.h>

// Attention_57406532878693: T=2048,B=32,D=1024,H=8,N=128,N2=16
#define T_  2048
#define B_  32
#define D_  1024
#define H_  8
#define N_  128
#define NK  16        // N2 gate width
#define TT  64        // t-tile per iteration in k_att
#define NT  (T_/TT)   // 32 tiles
#define XS  132       // LDS row stride for x tile (pad: 132%32=4 -> 2-way max)
#define PDS 68        // LDS row stride for dot partials
#define BD  (B_*D_)
#define BD4 (BD/4)
#define TCH 16        // t-chunks in mean kernel
#define TPC (T_/TCH)  // 128 t per chunk

// K1: partial column sums of hyp over t-chunks (deterministic, no atomics).
// grid (32, TCH) x 256: thread sums 128 t's of one float4 column.
__global__ __launch_bounds__(256) void k_mean(const float4* __restrict__ hyp4,
                                              float4* __restrict__ part4) {
    int c4 = blockIdx.x * 256 + threadIdx.x;     // [0, 8192) float4 columns
    int t0 = blockIdx.y * TPC;
    float4 s = make_float4(0.f, 0.f, 0.f, 0.f);
    for (int t = t0; t < t0 + TPC; ++t) {
        float4 v = hyp4[(size_t)t * BD4 + c4];
        s.x += v.x; s.y += v.y; s.z += v.z; s.w += v.w;
    }
    part4[blockIdx.y * BD4 + c4] = s;
}

// K2: finish mean, compute gw[b,h,k] = tanh(m . Wm_w[k] + Wm_b[k]) * Wh_w[k].
// (Wh_b omitted everywhere: softmax is shift-invariant.)
__global__ __launch_bounds__(128) void k_gw(const float* __restrict__ part,
                                            const float* __restrict__ Wm_w,
                                            const float* __restrict__ Wm_b,
                                            const float* __restrict__ Wh_w,
                                            float* __restrict__ gw) {
    __shared__ float m_l[N_];
    int bh = blockIdx.x;
    int b = bh >> 3, h = bh & 7;
    int tid = threadIdx.x;
    int col = b * D_ + h * N_ + tid;
    float s = 0.f;
    for (int ch = 0; ch < TCH; ++ch) s += part[ch * BD + col];
    m_l[tid] = s * (1.0f / (float)T_);
    __syncthreads();
    if (tid < NK) {
        float dot = Wm_b[tid];
        for (int n = 0; n < N_; ++n) dot = fmaf(m_l[n], Wm_w[tid * N_ + n], dot);
        gw[bh * NK + tid] = tanhf(dot) * Wh_w[tid];
    }
}

// K3: one block per (b,h). Single pass over the T x 128 slice with online
// softmax: stage 64-t tiles (global->reg early, reg->LDS after compute =
// async-stage split), gate dots with 4t x 4k x 32n register blocking,
// wave-0 shfl softmax update, per-thread weighted accumulation.
__global__ __launch_bounds__(256) void k_att(const float* __restrict__ hyp,
                                             const float* __restrict__ Ww,
                                             const float* __restrict__ Wb,
                                             const float* __restrict__ gw,
                                             float* __restrict__ out) {
    __shared__ float xs[TT * XS];       // 33792 B  x tile (padded rows)
    __shared__ float wl[NK * XS];       //  8448 B  W_w (padded rows)
    __shared__ float pd[TT * PDS];      // 17408 B  dot partials (reused as red)
    __shared__ float pl2[TT * 4];
    __shared__ float wexp_l[TT];
    __shared__ float wb_l[NK], gw_l[NK];
    __shared__ float fscale_s, zfin_s;

    const int tid = threadIdx.x;
    const int bh = blockIdx.x;
    const int b = bh >> 3, h = bh & 7;
    const float4* hyp4 = (const float4*)hyp;
    const int base4 = b * (D_ / 4) + h * (N_ / 4);

    // stage W_w into padded LDS rows
    for (int i = tid; i < NK * (N_ / 4); i += 256) {
        int k = i >> 5, n4 = i & 31;
        *(float4*)&wl[k * XS + n4 * 4] = ((const float4*)Ww)[k * (N_ / 4) + n4];
    }
    if (tid < NK) { wb_l[tid] = Wb[tid]; gw_l[tid] = gw[bh * NK + tid]; }

    // prologue: tile 0 global->reg->LDS
    float4 stg[8];
#pragma unroll
    for (int i = 0; i < 8; ++i) {
        int item = i * 256 + tid;
        int row = item >> 5, n4 = item & 31;
        stg[i] = hyp4[(size_t)row * BD4 + base4 + n4];
    }
#pragma unroll
    for (int i = 0; i < 8; ++i) {
        int item = i * 256 + tid;
        int row = item >> 5, n4 = item & 31;
        *(float4*)&xs[row * XS + n4 * 4] = stg[i];
    }

    const int t4 = tid & 15, kq = (tid >> 4) & 3, nq4 = tid >> 6;
    const int nn = tid & 127, hv = tid >> 7;
    const int nb = nq4 * 32;
    float M = -INFINITY, Z = 0.f;   // softmax state (wave 0 only meaningful)
    float cacc = 0.f;               // per-thread c partial for (nn, half=hv)

    for (int tile = 0; tile < NT; ++tile) {
        __syncthreads();            // xs (+wl on tile 0) visible
        if (tile + 1 < NT) {        // issue next tile's loads early (T14)
            int t0g = (tile + 1) * TT;
#pragma unroll
            for (int i = 0; i < 8; ++i) {
                int item = i * 256 + tid;
                int row = item >> 5, n4 = item & 31;
                stg[i] = hyp4[(size_t)(t0g + row) * BD4 + base4 + n4];
            }
        }
        // ---- phase 2: gate dots, thread = (t4, kq, nq4): 4t x 4k over 32 n
        float acc[4][4];
#pragma unroll
        for (int j = 0; j < 4; ++j)
#pragma unroll
            for (int jj = 0; jj < 4; ++jj) acc[j][jj] = 0.f;
        for (int i4 = 0; i4 < 8; ++i4) {
            int n = nb + i4 * 4;
            float4 xv[4], wv[4];
#pragma unroll
            for (int j = 0; j < 4; ++j)
                xv[j] = *(const float4*)&xs[(t4 + 16 * j) * XS + n];
#pragma unroll
            for (int jj = 0; jj < 4; ++jj)
                wv[jj] = *(const float4*)&wl[(kq * 4 + jj) * XS + n];
#pragma unroll
            for (int j = 0; j < 4; ++j)
#pragma unroll
                for (int jj = 0; jj < 4; ++jj) {
                    acc[j][jj] = fmaf(xv[j].x, wv[jj].x, acc[j][jj]);
                    acc[j][jj] = fmaf(xv[j].y, wv[jj].y, acc[j][jj]);
                    acc[j][jj] = fmaf(xv[j].z, wv[jj].z, acc[j][jj]);
                    acc[j][jj] = fmaf(xv[j].w, wv[jj].w, acc[j][jj]);
                }
        }
#pragma unroll
        for (int j = 0; j < 4; ++j)
#pragma unroll
            for (int jj = 0; jj < 4; ++jj)
                pd[(t4 + 16 * j) * PDS + (kq * 4 + jj) * 4 + nq4] = acc[j][jj];
        __syncthreads();
        // ---- phase 3: reduce partials -> logit contributions
        {
            int t = tid & 63, kq2 = tid >> 6;
            float pl = 0.f;
#pragma unroll
            for (int jj = 0; jj < 4; ++jj) {
                int k = kq2 * 4 + jj;
                float4 pv = *(const float4*)&pd[t * PDS + k * 4];
                float dot = pv.x + pv.y + pv.z + pv.w + wb_l[k];
                pl = fmaf(tanhf(dot), gw_l[k], pl);
            }
            pl2[t * 4 + kq2] = pl;
        }
        __syncthreads();
        // ---- online softmax update (wave 0: one lane per t)
        if (tid < TT) {
            float4 q = *(const float4*)&pl2[tid * 4];
            float l = q.x + q.y + q.z + q.w;
            float tmax = l;
#pragma unroll
            for (int mm = 1; mm < 64; mm <<= 1)
                tmax = fmaxf(tmax, __shfl_xor(tmax, mm, 64));
            float Mn = fmaxf(M, tmax);
            float p = expf(l - Mn);
            float ts = p;
#pragma unroll
            for (int mm = 1; mm < 64; mm <<= 1)
                ts += __shfl_xor(ts, mm, 64);
            float f = expf(M - Mn);
            Z = Z * f + ts;
            M = Mn;
            wexp_l[tid] = p;
            if (tid == 0) fscale_s = f;
        }
        __syncthreads();
        // ---- phase 4: rescale + weighted accumulation
        cacc *= fscale_s;
        for (int tt = 0; tt < 32; ++tt) {
            int t = hv * 32 + tt;
            cacc = fmaf(wexp_l[t], xs[t * XS + nn], cacc);
        }
        __syncthreads();            // all xs reads done before overwrite
        if (tile + 1 < NT) {
#pragma unroll
            for (int i = 0; i < 8; ++i) {
                int item = i * 256 + tid;
                int row = item >> 5, n4 = item & 31;
                *(float4*)&xs[row * XS + n4 * 4] = stg[i];
            }
        }
    }
    if (tid == 0) zfin_s = Z;
    float* red = pd;                // reuse pd as reduction buffer
    red[hv * 128 + nn] = cacc;
    __syncthreads();
    if (tid < 128) {
        out[b * D_ + h * N_ + tid] = (red[tid] + red[128 + tid]) / zfin_s;
    }
}

extern "C" void kernel_launch(void* const* d_in, const int* in_sizes, int n_in,
                              void* d_out, int out_size, void* d_ws, size_t ws_size,
                              hipStream_t stream) {
    const float* hyp = (const float*)d_in[0];
    const float* Ww  = (const float*)d_in[1];
    const float* Wb  = (const float*)d_in[2];
    const float* Wmw = (const float*)d_in[3];
    const float* Wmb = (const float*)d_in[4];
    const float* Whw = (const float*)d_in[5];
    // d_in[6] = Wh_b: unused (softmax shift-invariant)
    float* out  = (float*)d_out;
    float* part = (float*)d_ws;            // TCH*B*D floats = 2 MB
    float* gw   = part + (size_t)TCH * BD; // B*H*NK floats

    k_mean<<<dim3(32, TCH), 256, 0, stream>>>((const float4*)hyp, (float4*)part);
    k_gw<<<dim3(B_ * H_), 128, 0, stream>>>(part, Wmw, Wmb, Whw, gw);
    k_att<<<dim3(B_ * H_), 256, 0, stream>>>(hyp, Ww, Wb, gw, out);
}

// Round 2
// 183.100 us; speedup vs baseline: 1.1805x; 1.1805x over previous
//
#include <hip/hip_runtime.h>
#include <math.h>

// Attention_57406532878693: T=2048,B=32,D=1024,H=8,N=128,N2=16
#define T_   2048
#define B_   32
#define D_   1024
#define H_   8
#define N_   128
#define NK   16          // N2 gate width
#define TSPL 8           // T-splits per (b,h)
#define TBLK (T_/TSPL)   // 256 t per block
#define TT   32          // t-tile per iteration
#define NTL  (TBLK/TT)   // 8 tiles per block
#define XS   132         // xs row stride (floats); 132%32=4 -> balanced b128 banks
#define WS_  144         // wl row stride (floats)
#define WC   36          // wl 32-col chunk stride -> nq4 chunks on distinct banks
#define BD   (B_*D_)
#define BD4  (BD/4)
#define TCH  16          // t-chunks in mean kernel
#define TPC  (T_/TCH)    // 128 t per chunk
#define APS  136         // attp stride per split (128 c + M + Z + pad)

// K1: partial column sums of hyp over t-chunks (deterministic, no atomics).
__global__ __launch_bounds__(256) void k_mean(const float4* __restrict__ hyp4,
                                              float4* __restrict__ part4) {
    int c4 = blockIdx.x * 256 + threadIdx.x;     // [0, 8192) float4 columns
    int t0 = blockIdx.y * TPC;
    float4 a0 = {0,0,0,0}, a1 = {0,0,0,0}, a2 = {0,0,0,0}, a3 = {0,0,0,0};
    for (int t = t0; t < t0 + TPC; t += 4) {
        float4 v0 = hyp4[(size_t)(t+0) * BD4 + c4];
        float4 v1 = hyp4[(size_t)(t+1) * BD4 + c4];
        float4 v2 = hyp4[(size_t)(t+2) * BD4 + c4];
        float4 v3 = hyp4[(size_t)(t+3) * BD4 + c4];
        a0.x += v0.x; a0.y += v0.y; a0.z += v0.z; a0.w += v0.w;
        a1.x += v1.x; a1.y += v1.y; a1.z += v1.z; a1.w += v1.w;
        a2.x += v2.x; a2.y += v2.y; a2.z += v2.z; a2.w += v2.w;
        a3.x += v3.x; a3.y += v3.y; a3.z += v3.z; a3.w += v3.w;
    }
    float4 s;
    s.x = (a0.x + a1.x) + (a2.x + a3.x);
    s.y = (a0.y + a1.y) + (a2.y + a3.y);
    s.z = (a0.z + a1.z) + (a2.z + a3.z);
    s.w = (a0.w + a1.w) + (a2.w + a3.w);
    part4[blockIdx.y * BD4 + c4] = s;
}

// K2: finish mean, gw[b,h,k] = tanh(m . Wm_w[k] + Wm_b[k]) * Wh_w[k].
// (Wh_b omitted: softmax is shift-invariant.)
__global__ __launch_bounds__(128) void k_gw(const float* __restrict__ part,
                                            const float* __restrict__ Wm_w,
                                            const float* __restrict__ Wm_b,
                                            const float* __restrict__ Wh_w,
                                            float* __restrict__ gw) {
    __shared__ float m_l[N_];
    int bh = blockIdx.x;
    int b = bh >> 3, h = bh & 7;
    int tid = threadIdx.x;
    int col = b * D_ + h * N_ + tid;
    float s = 0.f;
    for (int ch = 0; ch < TCH; ++ch) s += part[ch * BD + col];
    m_l[tid] = s * (1.0f / (float)T_);
    __syncthreads();
    int k = tid >> 3, g = tid & 7;        // 8 lanes per k, lane bits 0..2 = g
    float d = 0.f;
    for (int i = 0; i < 16; ++i) {
        int n = g * 16 + i;
        d = fmaf(m_l[n], Wm_w[k * N_ + n], d);
    }
    d += __shfl_xor(d, 1, 64);
    d += __shfl_xor(d, 2, 64);
    d += __shfl_xor(d, 4, 64);
    if (g == 0) gw[bh * NK + k] = tanhf(d + Wm_b[k]) * Wh_w[k];
}

// K3: one block per (b,h,split). 256 t's per block, 32-t tiles, online softmax.
// lane = (t4:bits0-3, nq4:bits4-5), wave = kq. Dot n-reduction = 2 shfl_xor.
__global__ __launch_bounds__(256, 5) void k_att(const float* __restrict__ hyp,
                                                const float* __restrict__ Ww,
                                                const float* __restrict__ Wb,
                                                const float* __restrict__ gw,
                                                float* __restrict__ attp) {
    __shared__ float xs[TT * XS];        // 16896 B  x tile (also epilogue red)
    __shared__ float wl[NK * WS_];       //  9216 B  W_w padded chunks
    __shared__ float pl2[TT * 4];        //   512 B  per-k-wave logit partials
    __shared__ float wexp_l[TT];
    __shared__ float wb_l[NK], gw_l[NK];
    __shared__ float fscale_s;

    const int tid = threadIdx.x;
    const int blk = blockIdx.x;
    const int bh  = blk >> 3;            // 256 (b,h) pairs
    const int spl = blk & 7;
    const int b = bh >> 3, h = bh & 7;
    const int t0 = spl * TBLK;
    const float4* hyp4 = (const float4*)hyp;
    const int base4 = b * (D_ / 4) + h * (N_ / 4);

    // stage W_w into padded-chunk LDS: wl[k*144 + nc*36 + i4*4 ..]
    for (int i = tid; i < NK * 32; i += 256) {     // 512 float4
        int k = i >> 5, rem = i & 31, nc = rem >> 3, i4 = rem & 7;
        *(float4*)&wl[k * WS_ + nc * WC + i4 * 4] = ((const float4*)Ww)[k * 32 + rem];
    }
    if (tid < NK) { wb_l[tid] = Wb[tid]; gw_l[tid] = gw[bh * NK + tid]; }

    // prologue: tile 0 global->reg->LDS (4 float4/thread: 32 rows x 32 cols)
    float4 stg[4];
#pragma unroll
    for (int i = 0; i < 4; ++i) {
        int item = i * 256 + tid;
        int row = item >> 5, n4 = item & 31;
        stg[i] = hyp4[(size_t)(t0 + row) * BD4 + base4 + n4];
    }
#pragma unroll
    for (int i = 0; i < 4; ++i) {
        int item = i * 256 + tid;
        int row = item >> 5, n4 = item & 31;
        *(float4*)&xs[row * XS + n4 * 4] = stg[i];
    }

    const int t4  = tid & 15;
    const int nq4 = (tid >> 4) & 3;
    const int kq  = tid >> 6;
    const int n4a = tid & 31, tg = tid >> 5;   // accum-phase mapping
    float M = -INFINITY, Z = 0.f;              // softmax state (tid<32 lanes)
    float4 cacc = {0.f, 0.f, 0.f, 0.f};       // weighted-sum partial (4 n's)

    for (int tile = 0; tile < NTL; ++tile) {
        __syncthreads();                       // A: xs[tile] visible
        if (tile + 1 < NTL) {                  // issue next tile loads early
            int tg0 = t0 + (tile + 1) * TT;
#pragma unroll
            for (int i = 0; i < 4; ++i) {
                int item = i * 256 + tid;
                int row = item >> 5, n4 = item & 31;
                stg[i] = hyp4[(size_t)(tg0 + row) * BD4 + base4 + n4];
            }
        }
        // ---- gate dots: 2t x 4k x 32n per thread
        float acc[2][4];
#pragma unroll
        for (int j = 0; j < 2; ++j)
#pragma unroll
            for (int jj = 0; jj < 4; ++jj) acc[j][jj] = 0.f;
#pragma unroll
        for (int i4 = 0; i4 < 8; ++i4) {
            int n = nq4 * 32 + i4 * 4;
            float4 xv0 = *(const float4*)&xs[t4 * XS + n];
            float4 xv1 = *(const float4*)&xs[(t4 + 16) * XS + n];
            float4 wv[4];
#pragma unroll
            for (int jj = 0; jj < 4; ++jj)
                wv[jj] = *(const float4*)&wl[(kq * 4 + jj) * WS_ + nq4 * WC + i4 * 4];
#pragma unroll
            for (int jj = 0; jj < 4; ++jj) {
                acc[0][jj] = fmaf(xv0.x, wv[jj].x, acc[0][jj]);
                acc[0][jj] = fmaf(xv0.y, wv[jj].y, acc[0][jj]);
                acc[0][jj] = fmaf(xv0.z, wv[jj].z, acc[0][jj]);
                acc[0][jj] = fmaf(xv0.w, wv[jj].w, acc[0][jj]);
                acc[1][jj] = fmaf(xv1.x, wv[jj].x, acc[1][jj]);
                acc[1][jj] = fmaf(xv1.y, wv[jj].y, acc[1][jj]);
                acc[1][jj] = fmaf(xv1.z, wv[jj].z, acc[1][jj]);
                acc[1][jj] = fmaf(xv1.w, wv[jj].w, acc[1][jj]);
            }
        }
        // ---- reduce over nq4 (lane bits 4,5): butterfly
#pragma unroll
        for (int j = 0; j < 2; ++j)
#pragma unroll
            for (int jj = 0; jj < 4; ++jj) {
                acc[j][jj] += __shfl_xor(acc[j][jj], 16, 64);
                acc[j][jj] += __shfl_xor(acc[j][jj], 32, 64);
            }
        // ---- tanh distributed across nq4 lanes: lane handles jj = nq4
        {
            float d0 = (nq4 == 0) ? acc[0][0] : (nq4 == 1) ? acc[0][1]
                     : (nq4 == 2) ? acc[0][2] : acc[0][3];
            float d1 = (nq4 == 0) ? acc[1][0] : (nq4 == 1) ? acc[1][1]
                     : (nq4 == 2) ? acc[1][2] : acc[1][3];
            int k = kq * 4 + nq4;
            float pl0 = tanhf(d0 + wb_l[k]) * gw_l[k];
            float pl1 = tanhf(d1 + wb_l[k]) * gw_l[k];
            pl0 += __shfl_xor(pl0, 16, 64); pl0 += __shfl_xor(pl0, 32, 64);
            pl1 += __shfl_xor(pl1, 16, 64); pl1 += __shfl_xor(pl1, 32, 64);
            if (nq4 == 0) {
                pl2[t4 * 4 + kq]        = pl0;
                pl2[(t4 + 16) * 4 + kq] = pl1;
            }
        }
        __syncthreads();                       // B: pl2 ready
        // ---- online softmax (tid<32: one lane per t)
        if (tid < TT) {
            float4 q = *(const float4*)&pl2[tid * 4];
            float l = q.x + q.y + q.z + q.w;
            float tmax = l;
#pragma unroll
            for (int mm = 1; mm < 32; mm <<= 1)
                tmax = fmaxf(tmax, __shfl_xor(tmax, mm, 64));
            float Mn = fmaxf(M, tmax);
            float p = expf(l - Mn);
            float ts = p;
#pragma unroll
            for (int mm = 1; mm < 32; mm <<= 1)
                ts += __shfl_xor(ts, mm, 64);
            float f = expf(M - Mn);
            Z = Z * f + ts;
            M = Mn;
            wexp_l[tid] = p;
            if (tid == 0) fscale_s = f;
        }
        __syncthreads();                       // C: wexp/fscale ready
        // ---- rescale + weighted accumulation (thread = (n4a, tg): 4 t's)
        {
            float f = fscale_s;
            cacc.x *= f; cacc.y *= f; cacc.z *= f; cacc.w *= f;
#pragma unroll
            for (int tt = 0; tt < 4; ++tt) {
                int t = tg * 4 + tt;
                float w = wexp_l[t];
                float4 xv = *(const float4*)&xs[t * XS + n4a * 4];
                cacc.x = fmaf(w, xv.x, cacc.x);
                cacc.y = fmaf(w, xv.y, cacc.y);
                cacc.z = fmaf(w, xv.z, cacc.z);
                cacc.w = fmaf(w, xv.w, cacc.w);
            }
        }
        __syncthreads();                       // D: xs consumed
        if (tile + 1 < NTL) {
#pragma unroll
            for (int i = 0; i < 4; ++i) {
                int item = i * 256 + tid;
                int row = item >> 5, n4 = item & 31;
                *(float4*)&xs[row * XS + n4 * 4] = stg[i];
            }
        }
    }
    // epilogue: reduce cacc over 8 t-groups (reuse xs), write split partial
    *(float4*)&xs[(tg * 32 + n4a) * 4] = cacc;
    __syncthreads();
    if (tid < 32) {
        float4 s = {0.f, 0.f, 0.f, 0.f};
#pragma unroll
        for (int g = 0; g < 8; ++g) {
            float4 v = *(const float4*)&xs[(g * 32 + tid) * 4];
            s.x += v.x; s.y += v.y; s.z += v.z; s.w += v.w;
        }
        *(float4*)&attp[(size_t)blk * APS + tid * 4] = s;
        if (tid == 0) {
            attp[(size_t)blk * APS + 128] = M;
            attp[(size_t)blk * APS + 129] = Z;
        }
    }
}

// K4: merge TSPL split partials per (b,h): c = sum_i e^{Mi-M} ci / sum_i e^{Mi-M} Zi
__global__ __launch_bounds__(128) void k_red(const float* __restrict__ attp,
                                             float* __restrict__ out) {
    int bh = blockIdx.x, tid = threadIdx.x;
    float M = -INFINITY;
#pragma unroll
    for (int s = 0; s < TSPL; ++s)
        M = fmaxf(M, attp[(size_t)(bh * TSPL + s) * APS + 128]);
    float Z = 0.f, c = 0.f;
#pragma unroll
    for (int s = 0; s < TSPL; ++s) {
        const float* p = &attp[(size_t)(bh * TSPL + s) * APS];
        float e = expf(p[128] - M);
        Z = fmaf(p[129], e, Z);
        c = fmaf(p[tid], e, c);
    }
    out[bh * N_ + tid] = c / Z;
}

extern "C" void kernel_launch(void* const* d_in, const int* in_sizes, int n_in,
                              void* d_out, int out_size, void* d_ws, size_t ws_size,
                              hipStream_t stream) {
    const float* hyp = (const float*)d_in[0];
    const float* Ww  = (const float*)d_in[1];
    const float* Wb  = (const float*)d_in[2];
    const float* Wmw = (const float*)d_in[3];
    const float* Wmb = (const float*)d_in[4];
    const float* Whw = (const float*)d_in[5];
    // d_in[6] = Wh_b: unused (softmax shift-invariant)
    float* out  = (float*)d_out;
    float* part = (float*)d_ws;              // TCH*B*D floats = 2 MB
    float* gw   = part + (size_t)TCH * BD;   // 4096 floats, after part
    float* attp = part;                      // aliases part (consumed by k_gw)

    k_mean<<<dim3(32, TCH), 256, 0, stream>>>((const float4*)hyp, (float4*)part);
    k_gw<<<dim3(B_ * H_), 128, 0, stream>>>(part, Wmw, Wmb, Whw, gw);
    k_att<<<dim3(B_ * H_ * TSPL), 256, 0, stream>>>(hyp, Ww, Wb, gw, attp);
    k_red<<<dim3(B_ * H_), 128, 0, stream>>>(attp, out);
}

// Round 3
// 117.410 us; speedup vs baseline: 1.8409x; 1.5595x over previous
//
#include <hip/hip_runtime.h>
#include <math.h>

// Attention_57406532878693: T=2048,B=32,D=1024,H=8,N=128,N2=16
#define T_   2048
#define B_   32
#define D_   1024
#define H_   8
#define N_   128
#define NK   16          // N2 gate width
#define TSPL 8           // T-splits per (b,h)
#define TBLK (T_/TSPL)   // 256 t per block
#define BD   (B_*D_)
#define BD4  (BD/4)
#define TCH  16          // t-chunks in mean kernel
#define TPC  (T_/TCH)    // 128 t per chunk
#define APS  132         // attp stride per split (128 c + Z + pad)
#define LOG2E 1.4426950408889634f

typedef __attribute__((ext_vector_type(8))) short short8;   // bf16x8 frag
typedef __attribute__((ext_vector_type(4))) float f32x4;    // C/D frag

// split 8 fp32 (two float4) into truncated bf16 hi + bf16(lo) fragments
__device__ __forceinline__ void split_bf16(float4 a, float4 b,
                                           short8& hi, short8& lo) {
    union { uint32_t u[4]; short8 v; } H, L;
    uint32_t x0 = __float_as_uint(a.x), x1 = __float_as_uint(a.y);
    uint32_t x2 = __float_as_uint(a.z), x3 = __float_as_uint(a.w);
    uint32_t x4 = __float_as_uint(b.x), x5 = __float_as_uint(b.y);
    uint32_t x6 = __float_as_uint(b.z), x7 = __float_as_uint(b.w);
    H.u[0] = (x0 >> 16) | (x1 & 0xFFFF0000u);
    H.u[1] = (x2 >> 16) | (x3 & 0xFFFF0000u);
    H.u[2] = (x4 >> 16) | (x5 & 0xFFFF0000u);
    H.u[3] = (x6 >> 16) | (x7 & 0xFFFF0000u);
    float l0 = a.x - __uint_as_float(x0 & 0xFFFF0000u);
    float l1 = a.y - __uint_as_float(x1 & 0xFFFF0000u);
    float l2 = a.z - __uint_as_float(x2 & 0xFFFF0000u);
    float l3 = a.w - __uint_as_float(x3 & 0xFFFF0000u);
    float l4 = b.x - __uint_as_float(x4 & 0xFFFF0000u);
    float l5 = b.y - __uint_as_float(x5 & 0xFFFF0000u);
    float l6 = b.z - __uint_as_float(x6 & 0xFFFF0000u);
    float l7 = b.w - __uint_as_float(x7 & 0xFFFF0000u);
    L.u[0] = (__float_as_uint(l0) >> 16) | (__float_as_uint(l1) & 0xFFFF0000u);
    L.u[1] = (__float_as_uint(l2) >> 16) | (__float_as_uint(l3) & 0xFFFF0000u);
    L.u[2] = (__float_as_uint(l4) >> 16) | (__float_as_uint(l5) & 0xFFFF0000u);
    L.u[3] = (__float_as_uint(l6) >> 16) | (__float_as_uint(l7) & 0xFFFF0000u);
    hi = H.v; lo = L.v;
}

// K1: partial column sums of hyp over t-chunks (deterministic, no atomics).
__global__ __launch_bounds__(256) void k_mean(const float4* __restrict__ hyp4,
                                              float4* __restrict__ part4) {
    int c4 = blockIdx.x * 256 + threadIdx.x;     // [0, 8192) float4 columns
    int t0 = blockIdx.y * TPC;
    float4 a0 = {0,0,0,0}, a1 = {0,0,0,0}, a2 = {0,0,0,0}, a3 = {0,0,0,0};
    for (int t = t0; t < t0 + TPC; t += 4) {
        float4 v0 = hyp4[(size_t)(t+0) * BD4 + c4];
        float4 v1 = hyp4[(size_t)(t+1) * BD4 + c4];
        float4 v2 = hyp4[(size_t)(t+2) * BD4 + c4];
        float4 v3 = hyp4[(size_t)(t+3) * BD4 + c4];
        a0.x += v0.x; a0.y += v0.y; a0.z += v0.z; a0.w += v0.w;
        a1.x += v1.x; a1.y += v1.y; a1.z += v1.z; a1.w += v1.w;
        a2.x += v2.x; a2.y += v2.y; a2.z += v2.z; a2.w += v2.w;
        a3.x += v3.x; a3.y += v3.y; a3.z += v3.z; a3.w += v3.w;
    }
    float4 s;
    s.x = (a0.x + a1.x) + (a2.x + a3.x);
    s.y = (a0.y + a1.y) + (a2.y + a3.y);
    s.z = (a0.z + a1.z) + (a2.z + a3.z);
    s.w = (a0.w + a1.w) + (a2.w + a3.w);
    part4[blockIdx.y * BD4 + c4] = s;
}

// K2: finish mean, gw[b,h,k] = tanh(m . Wm_w[k] + Wm_b[k]) * Wh_w[k].
// (Wh_b omitted: softmax is shift-invariant.)
__global__ __launch_bounds__(128) void k_gw(const float* __restrict__ part,
                                            const float* __restrict__ Wm_w,
                                            const float* __restrict__ Wm_b,
                                            const float* __restrict__ Wh_w,
                                            float* __restrict__ gw) {
    __shared__ float m_l[N_];
    int bh = blockIdx.x;
    int b = bh >> 3, h = bh & 7;
    int tid = threadIdx.x;
    int col = b * D_ + h * N_ + tid;
    float s = 0.f;
    for (int ch = 0; ch < TCH; ++ch) s += part[ch * BD + col];
    m_l[tid] = s * (1.0f / (float)T_);
    __syncthreads();
    int k = tid >> 3, g = tid & 7;        // 8 lanes per k
    float d = 0.f;
    for (int i = 0; i < 16; ++i) {
        int n = g * 16 + i;
        d = fmaf(m_l[n], Wm_w[k * N_ + n], d);
    }
    d += __shfl_xor(d, 1, 64);
    d += __shfl_xor(d, 2, 64);
    d += __shfl_xor(d, 4, 64);
    if (g == 0) gw[bh * NK + k] = tanhf(d + Wm_b[k]) * Wh_w[k];
}

// K3: one block per (b,h,split). 4 waves; each wave owns independent 16-t
// MFMA steps. Logits bounded (|l|<=4) -> unshifted exp, NO online softmax,
// NO barriers in the main loop. x fragments loaded fp32 from global (used
// both for bf16 hi/lo MFMA operands and for the fp32 e-weighted accumulate).
__global__ __launch_bounds__(256) void k_att(const float* __restrict__ hyp,
                                             const float* __restrict__ Ww,
                                             const float* __restrict__ Wb,
                                             const float* __restrict__ gw,
                                             float* __restrict__ attp) {
    __shared__ float red[4 * N_];
    __shared__ float zred[4];

    const int tid  = threadIdx.x;
    const int lane = tid & 63;
    const int w    = tid >> 6;
    const int blk  = blockIdx.x;
    const int bh   = blk >> 3;           // 256 (b,h) pairs
    const int spl  = blk & 7;
    const int b = bh >> 3, h = bh & 7;
    const int t0 = spl * TBLK;
    const float4* hyp4 = (const float4*)hyp;
    const float4* Ww4  = (const float4*)Ww;
    const int base4 = b * (D_ / 4) + h * (N_ / 4);

    const int kk = lane & 15;            // gate-k (C col) & A-row index
    const int g  = lane >> 4;            // fragment group

    // W fragments (hi/lo bf16), bias, gate-weight: registers for whole kernel
    short8 wh[4], wl[4];
#pragma unroll
    for (int ks = 0; ks < 4; ++ks) {
        float4 wa = Ww4[kk * 32 + ks * 8 + g * 2];
        float4 wb4 = Ww4[kk * 32 + ks * 8 + g * 2 + 1];
        split_bf16(wa, wb4, wh[ks], wl[ks]);
    }
    const float wbr  = Wb[kk];
    const float gmwr = gw[bh * NK + kk];

    float4 cacc[8];
#pragma unroll
    for (int m = 0; m < 8; ++m) cacc[m] = make_float4(0.f, 0.f, 0.f, 0.f);
    float zacc = 0.f;

    for (int step = 0; step < TBLK / 64; ++step) {
        const int trow = t0 + step * 64 + w * 16 + kk;
        const size_t rbase = (size_t)trow * BD4 + base4;
        float4 xq[8];
#pragma unroll
        for (int ks = 0; ks < 4; ++ks) {
            xq[2*ks]   = hyp4[rbase + ks * 8 + g * 2];
            xq[2*ks+1] = hyp4[rbase + ks * 8 + g * 2 + 1];
        }
        // gate dots via 3-term bf16 MFMA (fp32-accurate)
        f32x4 acc = {0.f, 0.f, 0.f, 0.f};
#pragma unroll
        for (int ks = 0; ks < 4; ++ks) {
            short8 xh, xl;
            split_bf16(xq[2*ks], xq[2*ks+1], xh, xl);
            acc = __builtin_amdgcn_mfma_f32_16x16x32_bf16(xh, wh[ks], acc, 0, 0, 0);
            acc = __builtin_amdgcn_mfma_f32_16x16x32_bf16(xl, wh[ks], acc, 0, 0, 0);
            acc = __builtin_amdgcn_mfma_f32_16x16x32_bf16(xh, wl[ks], acc, 0, 0, 0);
        }
        // per lane: D[t=(lane>>4)*4+i][k=kk] -> tanh -> *gmw -> sum over k
        float pl[4];
#pragma unroll
        for (int i = 0; i < 4; ++i) {
            float d = acc[i] + wbr;
            float th = 1.f - 2.f * __frcp_rn(exp2f(d * (2.f * LOG2E)) + 1.f);
            pl[i] = th * gmwr;
        }
#pragma unroll
        for (int i = 0; i < 4; ++i) {
            pl[i] += __shfl_xor(pl[i], 1, 64);
            pl[i] += __shfl_xor(pl[i], 2, 64);
            pl[i] += __shfl_xor(pl[i], 4, 64);
            pl[i] += __shfl_xor(pl[i], 8, 64);
        }
        // unshifted exp (logits bounded by sum|gmw| <= 4)
        float e0 = exp2f(pl[0] * LOG2E), e1 = exp2f(pl[1] * LOG2E);
        float e2 = exp2f(pl[2] * LOG2E), e3 = exp2f(pl[3] * LOG2E);
        zacc += (e0 + e1) + (e2 + e3);
        // redistribute: lane needs e for its A-row kk
        int src = (kk >> 2) << 4;
        float s0 = __shfl(e0, src, 64), s1 = __shfl(e1, src, 64);
        float s2 = __shfl(e2, src, 64), s3 = __shfl(e3, src, 64);
        float E = (kk & 2) ? ((kk & 1) ? s3 : s2) : ((kk & 1) ? s1 : s0);
        // fp32 e-weighted accumulation (register-resident across all steps)
#pragma unroll
        for (int m = 0; m < 8; ++m) {
            cacc[m].x = fmaf(E, xq[m].x, cacc[m].x);
            cacc[m].y = fmaf(E, xq[m].y, cacc[m].y);
            cacc[m].z = fmaf(E, xq[m].z, cacc[m].z);
            cacc[m].w = fmaf(E, xq[m].w, cacc[m].w);
        }
    }
    // reduce cacc over t-rows (lane bits 0-3)
#pragma unroll
    for (int m = 0; m < 8; ++m) {
#pragma unroll
        for (int mask = 1; mask <= 8; mask <<= 1) {
            cacc[m].x += __shfl_xor(cacc[m].x, mask, 64);
            cacc[m].y += __shfl_xor(cacc[m].y, mask, 64);
            cacc[m].z += __shfl_xor(cacc[m].z, mask, 64);
            cacc[m].w += __shfl_xor(cacc[m].w, mask, 64);
        }
    }
    float z = zacc;
    z += __shfl_xor(z, 16, 64);
    z += __shfl_xor(z, 32, 64);
    if (kk == 0) {
#pragma unroll
        for (int m = 0; m < 8; ++m) {
            int nb = 32 * (m >> 1) + 8 * g + 4 * (m & 1);
            red[w * N_ + nb + 0] = cacc[m].x;
            red[w * N_ + nb + 1] = cacc[m].y;
            red[w * N_ + nb + 2] = cacc[m].z;
            red[w * N_ + nb + 3] = cacc[m].w;
        }
    }
    if (lane == 0) zred[w] = z;
    __syncthreads();
    if (tid < N_) {
        float s = (red[tid] + red[N_ + tid]) + (red[2*N_ + tid] + red[3*N_ + tid]);
        attp[(size_t)blk * APS + tid] = s;
    } else if (tid == N_) {
        attp[(size_t)blk * APS + N_] = (zred[0] + zred[1]) + (zred[2] + zred[3]);
    }
}

// K4: merge TSPL split partials per (b,h): c = sum ci / sum Zi
__global__ __launch_bounds__(128) void k_red(const float* __restrict__ attp,
                                             float* __restrict__ out) {
    int bh = blockIdx.x, tid = threadIdx.x;
    float Z = 0.f, c = 0.f;
#pragma unroll
    for (int s = 0; s < TSPL; ++s) {
        const float* p = &attp[(size_t)(bh * TSPL + s) * APS];
        Z += p[N_];
        c += p[tid];
    }
    out[bh * N_ + tid] = c / Z;
}

extern "C" void kernel_launch(void* const* d_in, const int* in_sizes, int n_in,
                              void* d_out, int out_size, void* d_ws, size_t ws_size,
                              hipStream_t stream) {
    const float* hyp = (const float*)d_in[0];
    const float* Ww  = (const float*)d_in[1];
    const float* Wb  = (const float*)d_in[2];
    const float* Wmw = (const float*)d_in[3];
    const float* Wmb = (const float*)d_in[4];
    const float* Whw = (const float*)d_in[5];
    // d_in[6] = Wh_b: unused (softmax shift-invariant)
    float* out  = (float*)d_out;
    float* part = (float*)d_ws;              // TCH*B*D floats = 2 MB
    float* gw   = part + (size_t)TCH * BD;   // 4096 floats, after part
    float* attp = part;                      // aliases part (consumed by k_gw);
                                             // 2048*132 floats < part size, gw safe

    k_mean<<<dim3(32, TCH), 256, 0, stream>>>((const float4*)hyp, (float4*)part);
    k_gw<<<dim3(B_ * H_), 128, 0, stream>>>(part, Wmw, Wmb, Whw, gw);
    k_att<<<dim3(B_ * H_ * TSPL), 256, 0, stream>>>(hyp, Ww, Wb, gw, attp);
    k_red<<<dim3(B_ * H_), 128, 0, stream>>>(attp, out);
}

// Round 5
// 111.099 us; speedup vs baseline: 1.9455x; 1.0568x over previous
//
#include <hip/hip_runtime.h>
#include <math.h>

// Attention_57406532878693: T=2048,B=32,D=1024,H=8,N=128,N2=16
#define T_   2048
#define B_   32
#define D_   1024
#define H_   8
#define N_   128
#define NK   16          // N2 gate width
#define TSPL 8           // T-splits per (b,h)
#define TBLK (T_/TSPL)   // 256 t per block
#define BD   (B_*D_)
#define BD4  (BD/4)
#define APS  132         // attp stride per unit (128 c + Z + pad)
#define LOG2E 1.4426950408889634f

typedef __attribute__((ext_vector_type(8))) short short8;   // bf16x8 frag
typedef __attribute__((ext_vector_type(4))) float f32x4;    // C/D frag

// split 8 fp32 (two float4) into truncated bf16 hi + bf16(lo) fragments
__device__ __forceinline__ void split_bf16(float4 a, float4 b,
                                           short8& hi, short8& lo) {
    union { uint32_t u[4]; short8 v; } H, L;
    uint32_t x0 = __float_as_uint(a.x), x1 = __float_as_uint(a.y);
    uint32_t x2 = __float_as_uint(a.z), x3 = __float_as_uint(a.w);
    uint32_t x4 = __float_as_uint(b.x), x5 = __float_as_uint(b.y);
    uint32_t x6 = __float_as_uint(b.z), x7 = __float_as_uint(b.w);
    H.u[0] = (x0 >> 16) | (x1 & 0xFFFF0000u);
    H.u[1] = (x2 >> 16) | (x3 & 0xFFFF0000u);
    H.u[2] = (x4 >> 16) | (x5 & 0xFFFF0000u);
    H.u[3] = (x6 >> 16) | (x7 & 0xFFFF0000u);
    float l0 = a.x - __uint_as_float(x0 & 0xFFFF0000u);
    float l1 = a.y - __uint_as_float(x1 & 0xFFFF0000u);
    float l2 = a.z - __uint_as_float(x2 & 0xFFFF0000u);
    float l3 = a.w - __uint_as_float(x3 & 0xFFFF0000u);
    float l4 = b.x - __uint_as_float(x4 & 0xFFFF0000u);
    float l5 = b.y - __uint_as_float(x5 & 0xFFFF0000u);
    float l6 = b.z - __uint_as_float(x6 & 0xFFFF0000u);
    float l7 = b.w - __uint_as_float(x7 & 0xFFFF0000u);
    L.u[0] = (__float_as_uint(l0) >> 16) | (__float_as_uint(l1) & 0xFFFF0000u);
    L.u[1] = (__float_as_uint(l2) >> 16) | (__float_as_uint(l3) & 0xFFFF0000u);
    L.u[2] = (__float_as_uint(l4) >> 16) | (__float_as_uint(l5) & 0xFFFF0000u);
    L.u[3] = (__float_as_uint(l6) >> 16) | (__float_as_uint(l7) & 0xFFFF0000u);
    hi = H.v; lo = L.v;
}

__device__ __forceinline__ float tanh_fast(float d) {
    return 1.f - 2.f * __frcp_rn(exp2f(d * (2.f * LOG2E)) + 1.f);
}

// load 8 float4 of x for one 16-t step (lane's t-row = t0+step*64+w*16+kk)
#define LOADX(dst, step_) { \
    const int trow_ = t0 + (step_) * 64 + w * 16 + kk; \
    const size_t rb_ = (size_t)trow_ * BD4 + base4; \
    (dst)[0] = hyp4[rb_ + g * 2];      (dst)[1] = hyp4[rb_ + g * 2 + 1]; \
    (dst)[2] = hyp4[rb_ + 8 + g * 2];  (dst)[3] = hyp4[rb_ + 8 + g * 2 + 1]; \
    (dst)[4] = hyp4[rb_ + 16 + g * 2]; (dst)[5] = hyp4[rb_ + 16 + g * 2 + 1]; \
    (dst)[6] = hyp4[rb_ + 24 + g * 2]; (dst)[7] = hyp4[rb_ + 24 + g * 2 + 1]; }

// K1: one block per (bh,spl). One x read: colsums -> part[blk][128],
// P[t][k] = tanh(x.Ww + b) -> Pbuf (fp32). x double-buffered in registers.
__global__ __launch_bounds__(256, 2) void k_p(const float* __restrict__ hyp,
                                              const float* __restrict__ Ww,
                                              const float* __restrict__ Wb,
                                              float* __restrict__ part,
                                              float* __restrict__ Pbuf) {
    __shared__ float red[4 * N_];
    const int tid  = threadIdx.x;
    const int lane = tid & 63;
    const int w    = tid >> 6;
    const int blk  = blockIdx.x;
    const int bh   = blk >> 3;
    const int spl  = blk & 7;
    const int b = bh >> 3, h = bh & 7;
    const int t0 = spl * TBLK;
    const float4* hyp4 = (const float4*)hyp;
    const float4* Ww4  = (const float4*)Ww;
    const int base4 = b * (D_ / 4) + h * (N_ / 4);
    const int kk = lane & 15;
    const int g  = lane >> 4;

    short8 wh[4], wl[4];
#pragma unroll
    for (int ks = 0; ks < 4; ++ks) {
        float4 wa  = Ww4[kk * 32 + ks * 8 + g * 2];
        float4 wb4 = Ww4[kk * 32 + ks * 8 + g * 2 + 1];
        split_bf16(wa, wb4, wh[ks], wl[ks]);
    }
    const float wbr = Wb[kk];

    float4 cs[8];
#pragma unroll
    for (int m = 0; m < 8; ++m) cs[m] = make_float4(0.f, 0.f, 0.f, 0.f);

    float4 xq[2][8];
    LOADX(xq[0], 0);
#pragma unroll
    for (int step = 0; step < 4; ++step) {
        const int cur = step & 1, nxt = cur ^ 1;
        if (step < 3) LOADX(xq[nxt], step + 1);
#pragma unroll
        for (int m = 0; m < 8; ++m) {
            cs[m].x += xq[cur][m].x; cs[m].y += xq[cur][m].y;
            cs[m].z += xq[cur][m].z; cs[m].w += xq[cur][m].w;
        }
        f32x4 acc = {0.f, 0.f, 0.f, 0.f};
#pragma unroll
        for (int ks = 0; ks < 4; ++ks) {
            short8 xh, xl;
            split_bf16(xq[cur][2*ks], xq[cur][2*ks+1], xh, xl);
            acc = __builtin_amdgcn_mfma_f32_16x16x32_bf16(xh, wh[ks], acc, 0, 0, 0);
            acc = __builtin_amdgcn_mfma_f32_16x16x32_bf16(xl, wh[ks], acc, 0, 0, 0);
            acc = __builtin_amdgcn_mfma_f32_16x16x32_bf16(xh, wl[ks], acc, 0, 0, 0);
        }
        // P[t = t0+step*64+w*16+g*4+i][kk]
        const int tl = t0 + step * 64 + w * 16 + g * 4;
        const size_t pb = ((size_t)bh * T_ + tl) * NK + kk;
#pragma unroll
        for (int i = 0; i < 4; ++i)
            Pbuf[pb + (size_t)i * NK] = tanh_fast(acc[i] + wbr);
    }
    // reduce colsums over kk (lane bits 0-3)
#pragma unroll
    for (int m = 0; m < 8; ++m) {
#pragma unroll
        for (int mask = 1; mask <= 8; mask <<= 1) {
            cs[m].x += __shfl_xor(cs[m].x, mask, 64);
            cs[m].y += __shfl_xor(cs[m].y, mask, 64);
            cs[m].z += __shfl_xor(cs[m].z, mask, 64);
            cs[m].w += __shfl_xor(cs[m].w, mask, 64);
        }
    }
    if (kk == 0) {
#pragma unroll
        for (int m = 0; m < 8; ++m) {
            int nb = 32 * (m >> 1) + 8 * g + 4 * (m & 1);
            red[w * N_ + nb + 0] = cs[m].x;
            red[w * N_ + nb + 1] = cs[m].y;
            red[w * N_ + nb + 2] = cs[m].z;
            red[w * N_ + nb + 3] = cs[m].w;
        }
    }
    __syncthreads();
    if (tid < N_)
        part[blk * N_ + tid] = (red[tid] + red[N_ + tid])
                             + (red[2*N_ + tid] + red[3*N_ + tid]);
}

// K3: one block per (bh,spl), reverse dispatch order (L3-freshest first).
// Prologue: mean from part + gm (k_gw folded in). Hot loop: logit from
// own P row (16 fma), exp, weighted accumulate. No MFMA/tanh/shuffles.
__global__ __launch_bounds__(256, 2) void k_att(const float* __restrict__ hyp,
                                                const float* __restrict__ part,
                                                const float* __restrict__ Wmw,
                                                const float* __restrict__ Wmb,
                                                const float* __restrict__ Whw,
                                                const float* __restrict__ Pbuf,
                                                float* __restrict__ attp) {
    __shared__ float red[4 * N_];
    __shared__ float zred[4];
    __shared__ float m_l[N_];
    __shared__ float gw_l[NK];
    const int tid  = threadIdx.x;
    const int lane = tid & 63;
    const int w    = tid >> 6;
    const int blk  = (B_ * H_ * TSPL - 1) - (int)blockIdx.x;
    const int bh   = blk >> 3;
    const int spl  = blk & 7;
    const int b = bh >> 3, h = bh & 7;
    const int t0 = spl * TBLK;
    const float4* hyp4  = (const float4*)hyp;
    const float4* Pbuf4 = (const float4*)Pbuf;
    const int base4 = b * (D_ / 4) + h * (N_ / 4);
    const int kk = lane & 15;
    const int g  = lane >> 4;

    // mean for this bh
    if (tid < N_) {
        float s = 0.f;
#pragma unroll
        for (int s8 = 0; s8 < TSPL; ++s8) s += part[(bh * TSPL + s8) * N_ + tid];
        m_l[tid] = s * (1.f / (float)T_);
    }
    __syncthreads();
    // gm: gw_l[k] = tanh(m.Wmw_k + Wmb_k) * Whw_k
    if (tid < N_) {
        int k = tid >> 3, g3 = tid & 7;
        float dsum = 0.f;
#pragma unroll
        for (int i = 0; i < 16; ++i) {
            int n = g3 * 16 + i;
            dsum = fmaf(m_l[n], Wmw[k * N_ + n], dsum);
        }
        dsum += __shfl_xor(dsum, 1, 64);
        dsum += __shfl_xor(dsum, 2, 64);
        dsum += __shfl_xor(dsum, 4, 64);
        if (g3 == 0) gw_l[k] = tanhf(dsum + Wmb[k]) * Whw[k];
    }
    __syncthreads();
    float gmv[NK];
#pragma unroll
    for (int j = 0; j < NK; ++j) gmv[j] = gw_l[j];

    float4 xq[2][8], pr[2][4];
    LOADX(xq[0], 0);
    {
        const int trow_ = t0 + w * 16 + kk;
        const size_t pb_ = (size_t)(bh * T_ + trow_) * 4;
        pr[0][0] = Pbuf4[pb_];     pr[0][1] = Pbuf4[pb_ + 1];
        pr[0][2] = Pbuf4[pb_ + 2]; pr[0][3] = Pbuf4[pb_ + 3];
    }
    float4 cacc[8];
#pragma unroll
    for (int m = 0; m < 8; ++m) cacc[m] = make_float4(0.f, 0.f, 0.f, 0.f);
    float zacc = 0.f;

#pragma unroll
    for (int step = 0; step < 4; ++step) {
        const int cur = step & 1, nxt = cur ^ 1;
        if (step < 3) {
            LOADX(xq[nxt], step + 1);
            const int trow_ = t0 + (step + 1) * 64 + w * 16 + kk;
            const size_t pb_ = (size_t)(bh * T_ + trow_) * 4;
            pr[nxt][0] = Pbuf4[pb_];     pr[nxt][1] = Pbuf4[pb_ + 1];
            pr[nxt][2] = Pbuf4[pb_ + 2]; pr[nxt][3] = Pbuf4[pb_ + 3];
        }
        // logit for this lane's t-row (unshifted exp: |logit| <= 4)
        float lg = 0.f;
#pragma unroll
        for (int q = 0; q < 4; ++q) {
            lg = fmaf(pr[cur][q].x, gmv[4*q + 0], lg);
            lg = fmaf(pr[cur][q].y, gmv[4*q + 1], lg);
            lg = fmaf(pr[cur][q].z, gmv[4*q + 2], lg);
            lg = fmaf(pr[cur][q].w, gmv[4*q + 3], lg);
        }
        float e = exp2f(lg * LOG2E);
        zacc += e;
#pragma unroll
        for (int m = 0; m < 8; ++m) {
            cacc[m].x = fmaf(e, xq[cur][m].x, cacc[m].x);
            cacc[m].y = fmaf(e, xq[cur][m].y, cacc[m].y);
            cacc[m].z = fmaf(e, xq[cur][m].z, cacc[m].z);
            cacc[m].w = fmaf(e, xq[cur][m].w, cacc[m].w);
        }
    }
    // reduce cacc and z over kk (lane bits 0-3)
#pragma unroll
    for (int m = 0; m < 8; ++m) {
#pragma unroll
        for (int mask = 1; mask <= 8; mask <<= 1) {
            cacc[m].x += __shfl_xor(cacc[m].x, mask, 64);
            cacc[m].y += __shfl_xor(cacc[m].y, mask, 64);
            cacc[m].z += __shfl_xor(cacc[m].z, mask, 64);
            cacc[m].w += __shfl_xor(cacc[m].w, mask, 64);
        }
    }
    float z = zacc;
    z += __shfl_xor(z, 1, 64);
    z += __shfl_xor(z, 2, 64);
    z += __shfl_xor(z, 4, 64);
    z += __shfl_xor(z, 8, 64);
    if (kk == 0) {
#pragma unroll
        for (int m = 0; m < 8; ++m) {
            int nb = 32 * (m >> 1) + 8 * g + 4 * (m & 1);
            red[w * N_ + nb + 0] = cacc[m].x;
            red[w * N_ + nb + 1] = cacc[m].y;
            red[w * N_ + nb + 2] = cacc[m].z;
            red[w * N_ + nb + 3] = cacc[m].w;
        }
    }
    if (lane == 0) zred[w] = z;
    __syncthreads();
    if (tid < N_) {
        attp[(size_t)blk * APS + tid] =
            (red[tid] + red[N_ + tid]) + (red[2*N_ + tid] + red[3*N_ + tid]);
    } else if (tid == N_) {
        attp[(size_t)blk * APS + N_] =
            (zred[0] + zred[1]) + (zred[2] + zred[3]);
    }
}

// K4: merge TSPL split partials per (b,h): c = sum ci / sum Zi
__global__ __launch_bounds__(128) void k_red(const float* __restrict__ attp,
                                             float* __restrict__ out) {
    int bh = blockIdx.x, tid = threadIdx.x;
    float Z = 0.f, c = 0.f;
#pragma unroll
    for (int s = 0; s < TSPL; ++s) {
        const float* pp = &attp[(size_t)(bh * TSPL + s) * APS];
        Z += pp[N_];
        c += pp[tid];
    }
    out[bh * N_ + tid] = c / Z;
}

extern "C" void kernel_launch(void* const* d_in, const int* in_sizes, int n_in,
                              void* d_out, int out_size, void* d_ws, size_t ws_size,
                              hipStream_t stream) {
    const float* hyp = (const float*)d_in[0];
    const float* Ww  = (const float*)d_in[1];
    const float* Wb  = (const float*)d_in[2];
    const float* Wmw = (const float*)d_in[3];
    const float* Wmb = (const float*)d_in[4];
    const float* Whw = (const float*)d_in[5];
    // d_in[6] = Wh_b: unused (softmax shift-invariant)
    float* out  = (float*)d_out;
    float* part = (float*)d_ws;                  // 2048*128 f  = 1 MB
    float* attp = part + 2048 * N_;              // 2048*132 f ~= 1.06 MB
    float* Pbuf = part + (1 << 20);              // +4 MB offset: 32 MB P

    k_p  <<<dim3(B_ * H_ * TSPL), 256, 0, stream>>>(hyp, Ww, Wb, part, Pbuf);
    k_att<<<dim3(B_ * H_ * TSPL), 256, 0, stream>>>(hyp, part, Wmw, Wmb, Whw,
                                                    Pbuf, attp);
    k_red<<<dim3(B_ * H_), 128, 0, stream>>>(attp, out);
}